// Round 4
// baseline (165.097 us; speedup 1.0000x reference)
//
#include <hip/hip_runtime.h>
#include <hip/hip_cooperative_groups.h>
#include <stdint.h>

namespace cg = cooperative_groups;

// ---------------- problem constants ----------------
#define B_ROWS 16384
#define NV 100000
#define NH 400
#define ZPAD 416
#define EPS 1e-5f

typedef __attribute__((ext_vector_type(8))) short short8;
typedef __attribute__((ext_vector_type(4))) float f32x4;
typedef __attribute__((ext_vector_type(4))) unsigned int uint4v;

__device__ inline float bf2f(unsigned short u) {
    union { unsigned int i; float f; } v; v.i = (unsigned int)u << 16; return v.f;
}
__device__ inline unsigned short f2bf(float f) {
    union { float f; unsigned int i; } v; v.f = f;
    unsigned int r = (v.i + 0x7fff + ((v.i >> 16) & 1)) >> 16;
    return (unsigned short)r;
}

// ---------------- ws layout (bytes) ----------------
// Z1 : bf16 [16384][416] = 13,631,488
// Z2 : bf16 [16384][400] = 13,107,200
// W1s: bf16 staged [14][4][448][8] = 401,408
// W2s: bf16 staged [13][4][448][8] = 372,736
// base: f32 [16384] ; st: f32 gsum1,gsq1,gsum2,gsq2 (416 each)
#define Z1_OFF   0
#define Z2_OFF   13631488
#define W1S_OFF  26738688
#define W2S_OFF  27140096
#define BASE_OFF 27512832
#define ST_OFF   27578368

struct SmemPool {
    unsigned short b_s[2][14336];                 // 57,344 B (W tile dbuf)
    union {
        struct { float S[4][416]; float Q[4][416]; } red;       // 13,312 B
        struct { int xcat[1664]; float dense[1024]; float wd[16]; } gat; // 10,816 B
    } u;
    float alpha_s[416], beta_s[416];              // 3,328 B
};  // total 73,984 B -> 2 blocks/CU

// ---- shared GEMM epilogue: +bias, bf16 store, column stats ----
__device__ __forceinline__ void gemm_epilogue(
    SmemPool& sm, f32x4* acc, int tid, int m0,
    const float* __restrict__ bias, unsigned short* __restrict__ Z, int ldz,
    bool padZ, float* __restrict__ gsum, float* __restrict__ gsq)
{
    const int lane = tid & 63, wv = tid >> 6;
    const int rowgrp = wv & 3, nhalf = wv >> 2;
    const int l15 = lane & 15, qh = lane >> 4;
    const int c0 = nhalf * 208;
    const int NFRAG = nhalf ? 12 : 13;

    #pragma unroll
    for (int nn = 0; nn < 13; ++nn) {
        if (nn < NFRAG) {
            int col = c0 + nn * 16 + l15;
            float bv = bias[col];
            float ps = 0.f, pq = 0.f;
            #pragma unroll
            for (int q = 0; q < 4; ++q) {
                float v = acc[nn][q] + bv;
                ps += v; pq += v * v;
                Z[(size_t)(m0 + rowgrp * 16 + qh * 4 + q) * ldz + col] = f2bf(v);
            }
            ps += __shfl_xor(ps, 16, 64); ps += __shfl_xor(ps, 32, 64);
            pq += __shfl_xor(pq, 16, 64); pq += __shfl_xor(pq, 32, 64);
            if (lane < 16) { sm.u.red.S[rowgrp][col] = ps; sm.u.red.Q[rowgrp][col] = pq; }
        }
    }
    if (padZ && nhalf == 1) {
        int col = NH + l15;
        if (col < ldz) {
            #pragma unroll
            for (int q = 0; q < 4; ++q)
                Z[(size_t)(m0 + rowgrp * 16 + qh * 4 + q) * ldz + col] = 0;
        }
    }
    __syncthreads();
    for (int c = tid; c < NH; c += 512) {
        atomicAdd(&gsum[c], sm.u.red.S[0][c] + sm.u.red.S[1][c] + sm.u.red.S[2][c] + sm.u.red.S[3][c]);
        atomicAdd(&gsq[c],  sm.u.red.Q[0][c] + sm.u.red.Q[1][c] + sm.u.red.Q[2][c] + sm.u.red.Q[3][c]);
    }
}

// =====================================================================
// mega kernel: 256 blocks x 512 threads, cooperative.
// phase0: W prep + stat zero + per-block xcat/dense LDS staging
// phase1: GEMM1 with fused embedding gather + FM base terms
// phase2: GEMM2 with fused BN1+ReLU on A
// phase3: final dot with fused BN2+ReLU
// =====================================================================
__global__ __launch_bounds__(512, 4) void deepfm_mega(
    const int* __restrict__ Xcat, const float* __restrict__ Xd,
    const float* __restrict__ fm1, const float* __restrict__ emb,
    const float* __restrict__ Wd, const float* __restrict__ bd,
    const float* __restrict__ W1, const float* __restrict__ b1,
    const float* __restrict__ g1, const float* __restrict__ be1,
    const float* __restrict__ W2, const float* __restrict__ b2,
    const float* __restrict__ g2, const float* __restrict__ be2,
    const float* __restrict__ W3, const float* __restrict__ b3,
    unsigned short* __restrict__ Z1, unsigned short* __restrict__ Z2,
    unsigned short* __restrict__ W1s, unsigned short* __restrict__ W2s,
    float* __restrict__ base, float* __restrict__ st, float* __restrict__ out)
{
    cg::grid_group grid = cg::this_grid();
    __shared__ SmemPool sm;

    const int tid = threadIdx.x;
    const int bid = blockIdx.x;
    const int lane = tid & 63;
    const int wv = tid >> 6;
    const int rowgrp = wv & 3, nhalf = wv >> 2;
    const int l15 = lane & 15, qh = lane >> 4;
    const int m0 = bid * 64;
    const int rloc = rowgrp * 16 + l15;
    const int arow = m0 + rloc;
    const int c0 = nhalf * 208;
    const int NFRAG = nhalf ? 12 : 13;

    // ================= phase 0: prep + staging =================
    {
        int c = bid * 512 + tid;
        if (c < 48384) {
            const float* W; unsigned short* dst; int K; int cc;
            if (c < 25088) { W = W1; dst = W1s; K = 429; cc = c; }
            else           { W = W2; dst = W2s; K = 400; cc = c - 25088; }
            int n  = cc % 448;
            int q  = (cc / 448) & 3;
            int kt = cc / 1792;
            unsigned short o[8];
            #pragma unroll
            for (int j = 0; j < 8; ++j) {
                int k = kt * 32 + q * 8 + j;
                float v = (n < NH && k < K) ? W[(size_t)k * NH + n] : 0.f;
                o[j] = f2bf(v);
            }
            *(uint4v*)(dst + (size_t)cc * 8) = *(uint4v*)o;
        } else if (c < 48384 + 1664) {
            st[c - 48384] = 0.f;
        }
        // per-block staging of categorical idx + dense rows
        for (int i = tid; i < 1664; i += 512)
            sm.u.gat.xcat[i] = Xcat[(size_t)m0 * 26 + i];
        for (int i = tid; i < 832; i += 512) {
            int r = i / 13, cc2 = i % 13;
            sm.u.gat.dense[r * 16 + cc2] = Xd[(size_t)m0 * 13 + i];
        }
        for (int i = tid; i < 192; i += 512)
            sm.u.gat.dense[(i / 3) * 16 + 13 + (i % 3)] = 0.f;
        if (tid < 16) sm.u.gat.wd[tid] = (tid < 13) ? Wd[tid] : 0.f;
    }
    __syncthreads();

    // gather-tile loader: tile kt<13 -> random 32B emb load; kt=13 -> dense
    auto ld_tile = [&](int kt, float (&v)[8]) {
        if (kt < 13) {
            int f = 2 * kt + (qh >> 1);
            int idx = sm.u.gat.xcat[rloc * 26 + f];
            const float* p = emb + (((size_t)f * NV + (size_t)idx) << 4) + ((qh & 1) << 3);
            f32x4 x0 = *(const f32x4*)p;
            f32x4 x1 = *(const f32x4*)(p + 4);
            v[0] = x0[0]; v[1] = x0[1]; v[2] = x0[2]; v[3] = x0[3];
            v[4] = x1[0]; v[5] = x1[1]; v[6] = x1[2]; v[7] = x1[3];
        } else {
            #pragma unroll
            for (int j = 0; j < 8; ++j)
                v[j] = (qh < 2) ? sm.u.gat.dense[rloc * 16 + ((qh & 1) << 3) + j] : 0.f;
        }
    };

    // preload tiles 0/1 + FM scalar terms (hides under phase0/grid sync)
    float va[8], vb[8];
    ld_tile(0, va);
    ld_tile(1, vb);
    float fmsum = 0.f, dsum = 0.f;
    if (nhalf == 0) {
        for (int f = qh; f < 26; f += 4)
            fmsum += fm1[(size_t)f * NV + sm.u.gat.xcat[rloc * 26 + f]];
        if (qh < 2) {
            #pragma unroll
            for (int j = 0; j < 8; ++j)
                dsum += sm.u.gat.dense[rloc * 16 + (qh & 1) * 8 + j] * sm.u.gat.wd[(qh & 1) * 8 + j];
        }
    }

    grid.sync();

    // ================= phase 1: GEMM1 + FM =================
    f32x4 acc[13];
    #pragma unroll
    for (int i = 0; i < 13; ++i) acc[i] = f32x4{0.f, 0.f, 0.f, 0.f};
    uint4v rg[4];
    #pragma unroll
    for (int i = 0; i < 4; ++i) {
        int c = i * 512 + tid;
        if (c < 1792) rg[i] = *(const uint4v*)(W1s + (size_t)c * 8);
    }
    float s8[8] = {0.f, 0.f, 0.f, 0.f, 0.f, 0.f, 0.f, 0.f};
    float ssacc = 0.f;

    auto body1 = [&](int kt, int par, float (&v)[8]) {
        __syncthreads();
        #pragma unroll
        for (int i = 0; i < 4; ++i) {
            int c = i * 512 + tid;
            if (c < 1792) *(uint4v*)(&sm.b_s[par][(size_t)c * 8]) = rg[i];
        }
        if (kt + 1 < 14) {
            #pragma unroll
            for (int i = 0; i < 4; ++i) {
                int c = i * 512 + tid;
                if (c < 1792)
                    rg[i] = *(const uint4v*)(W1s + (size_t)(kt + 1) * 14336 + (size_t)c * 8);
            }
        }
        if (kt < 13 && nhalf == 0) {
            #pragma unroll
            for (int j = 0; j < 8; ++j) { s8[j] += v[j]; ssacc += v[j] * v[j]; }
        }
        short8 af;
        #pragma unroll
        for (int j = 0; j < 8; ++j) af[j] = (short)f2bf(v[j]);
        if (kt + 2 < 14) ld_tile(kt + 2, v);     // depth-2 gather prefetch
        __syncthreads();
        const unsigned short* bb = &sm.b_s[par][(size_t)(qh * 448 + c0 + l15) * 8];
        #pragma unroll
        for (int nn = 0; nn < 13; ++nn) {
            if (nn < NFRAG) {
                short8 bf = *(const short8*)(bb + nn * 128);
                acc[nn] = __builtin_amdgcn_mfma_f32_16x16x32_bf16(af, bf, acc[nn], 0, 0, 0);
            }
        }
    };
    for (int kt2 = 0; kt2 < 14; kt2 += 2) {
        body1(kt2, 0, va);
        body1(kt2 + 1, 1, vb);
    }

    // FM base: ix = sum_k (s_k^2) - sum ss ; cross-qh reduce
    if (nhalf == 0) {
        float red = 0.f;
        #pragma unroll
        for (int j = 0; j < 8; ++j) {
            float sf = s8[j] + __shfl_xor(s8[j], 32, 64);
            red += sf * sf;
        }
        red -= (ssacc + __shfl_xor(ssacc, 32, 64));
        red += __shfl_xor(red, 16, 64);
        float fr = fmsum + __shfl_xor(fmsum, 16, 64);
        fr += __shfl_xor(fr, 32, 64);
        float dr = dsum + __shfl_xor(dsum, 16, 64);
        dr += __shfl_xor(dr, 32, 64);
        if (qh == 0) base[arow] = 0.5f * red + fr + dr + bd[0];
    }
    gemm_epilogue(sm, acc, tid, m0, b1, Z1, ZPAD, true, st, st + 416);

    grid.sync();

    // ================= phase 2: GEMM2 (+BN1 on A) =================
    {
        const float* gs = st; const float* gq = st + 416;
        for (int c = tid; c < ZPAD; c += 512) {
            float a = 0.f, b = 0.f;
            if (c < NH) {
                float mean = gs[c] * (1.f / B_ROWS);
                float var  = gq[c] * (1.f / B_ROWS) - mean * mean;
                a = g1[c] * rsqrtf(var + EPS);
                b = be1[c] - mean * a;
            }
            sm.alpha_s[c] = a; sm.beta_s[c] = b;
        }
    }
    #pragma unroll
    for (int i = 0; i < 13; ++i) acc[i] = f32x4{0.f, 0.f, 0.f, 0.f};
    #pragma unroll
    for (int i = 0; i < 4; ++i) {
        int c = i * 512 + tid;
        if (c < 1792) rg[i] = *(const uint4v*)(W2s + (size_t)c * 8);
    }
    short8 af_next = *(const short8*)(Z1 + (size_t)arow * ZPAD + qh * 8);

    for (int kt = 0; kt < 13; ++kt) {
        __syncthreads();
        #pragma unroll
        for (int i = 0; i < 4; ++i) {
            int c = i * 512 + tid;
            if (c < 1792) *(uint4v*)(&sm.b_s[kt & 1][(size_t)c * 8]) = rg[i];
        }
        if (kt + 1 < 13) {
            #pragma unroll
            for (int i = 0; i < 4; ++i) {
                int c = i * 512 + tid;
                if (c < 1792)
                    rg[i] = *(const uint4v*)(W2s + (size_t)(kt + 1) * 14336 + (size_t)c * 8);
            }
        }
        short8 af = af_next;
        if (kt + 1 < 13)
            af_next = *(const short8*)(Z1 + (size_t)arow * ZPAD + (kt + 1) * 32 + qh * 8);
        int k0 = kt * 32 + qh * 8;
        #pragma unroll
        for (int j = 0; j < 8; ++j) {
            float f = bf2f((unsigned short)af[j]);
            f = fmaxf(0.f, sm.alpha_s[k0 + j] * f + sm.beta_s[k0 + j]);
            af[j] = (short)f2bf(f);
        }
        __syncthreads();
        const unsigned short* bb = &sm.b_s[kt & 1][(size_t)(qh * 448 + c0 + l15) * 8];
        #pragma unroll
        for (int nn = 0; nn < 13; ++nn) {
            if (nn < NFRAG) {
                short8 bf = *(const short8*)(bb + nn * 128);
                acc[nn] = __builtin_amdgcn_mfma_f32_16x16x32_bf16(af, bf, acc[nn], 0, 0, 0);
            }
        }
    }
    gemm_epilogue(sm, acc, tid, m0, b2, Z2, 400, false, st + 832, st + 1248);

    grid.sync();

    // ================= phase 3: final =================
    {
        const float* gs = st + 832; const float* gq = st + 1248;
        float* w3s = sm.u.red.S[0];
        for (int c = tid; c < NH; c += 512) {
            float mean = gs[c] * (1.f / B_ROWS);
            float var  = gq[c] * (1.f / B_ROWS) - mean * mean;
            float a = g2[c] * rsqrtf(var + EPS);
            sm.alpha_s[c] = a;
            sm.beta_s[c]  = be2[c] - mean * a;
            w3s[c] = W3[c];
        }
        __syncthreads();
        bool act2 = lane < 50;
        int cb = lane * 8;
        float al[8], bbv[8], w3[8];
        #pragma unroll
        for (int j = 0; j < 8; ++j) {
            al[j]  = act2 ? sm.alpha_s[cb + j] : 0.f;
            bbv[j] = act2 ? sm.beta_s[cb + j] : 0.f;
            w3[j]  = act2 ? w3s[cb + j] : 0.f;
        }
        int r0 = m0 + wv * 8;
        float bias3 = b3[0];
        for (int t = 0; t < 8; t += 2) {
            int r = r0 + t;
            float a0 = 0.f, a1 = 0.f;
            if (act2) {
                short8 z0 = *(const short8*)(Z2 + (size_t)r * 400 + cb);
                short8 z1 = *(const short8*)(Z2 + (size_t)(r + 1) * 400 + cb);
                #pragma unroll
                for (int j = 0; j < 8; ++j) {
                    a0 += fmaxf(0.f, al[j] * bf2f((unsigned short)z0[j]) + bbv[j]) * w3[j];
                    a1 += fmaxf(0.f, al[j] * bf2f((unsigned short)z1[j]) + bbv[j]) * w3[j];
                }
            }
            #pragma unroll
            for (int off = 32; off; off >>= 1) {
                a0 += __shfl_xor(a0, off, 64);
                a1 += __shfl_xor(a1, off, 64);
            }
            if (lane == 0) out[r] = base[r] + a0 + bias3;
            if (lane == 1) out[r + 1] = base[r + 1] + a1 + bias3;
        }
    }
}

// =====================================================================
extern "C" void kernel_launch(void* const* d_in, const int* in_sizes, int n_in,
                              void* d_out, int out_size, void* d_ws, size_t ws_size,
                              hipStream_t stream)
{
    const int*   Xcat = (const int*)d_in[0];
    const float* Xd   = (const float*)d_in[1];
    const float* fm1  = (const float*)d_in[2];
    const float* emb  = (const float*)d_in[3];
    const float* Wd   = (const float*)d_in[4];
    const float* bd   = (const float*)d_in[5];
    const float* W1   = (const float*)d_in[6];
    const float* b1   = (const float*)d_in[7];
    const float* g1   = (const float*)d_in[8];
    const float* be1  = (const float*)d_in[9];
    const float* W2   = (const float*)d_in[10];
    const float* b2   = (const float*)d_in[11];
    const float* g2   = (const float*)d_in[12];
    const float* be2  = (const float*)d_in[13];
    const float* W3   = (const float*)d_in[14];
    const float* b3   = (const float*)d_in[15];

    char* ws = (char*)d_ws;
    unsigned short* Z1  = (unsigned short*)(ws + Z1_OFF);
    unsigned short* Z2  = (unsigned short*)(ws + Z2_OFF);
    unsigned short* W1s = (unsigned short*)(ws + W1S_OFF);
    unsigned short* W2s = (unsigned short*)(ws + W2S_OFF);
    float* base = (float*)(ws + BASE_OFF);
    float* st   = (float*)(ws + ST_OFF);
    float* out  = (float*)d_out;

    void* args[] = {
        (void*)&Xcat, (void*)&Xd, (void*)&fm1, (void*)&emb,
        (void*)&Wd, (void*)&bd, (void*)&W1, (void*)&b1, (void*)&g1, (void*)&be1,
        (void*)&W2, (void*)&b2, (void*)&g2, (void*)&be2, (void*)&W3, (void*)&b3,
        (void*)&Z1, (void*)&Z2, (void*)&W1s, (void*)&W2s,
        (void*)&base, (void*)&st, (void*)&out
    };
    hipLaunchCooperativeKernel((const void*)deepfm_mega, dim3(256), dim3(512),
                               args, 0, stream);
}

// Round 5
// 82.519 us; speedup vs baseline: 2.0007x; 2.0007x over previous
//
#include <hip/hip_runtime.h>
#include <stdint.h>

// ---------------- problem constants ----------------
#define B_ROWS 16384
#define NF 26
#define NV 100000
#define ND 13
#define NH 400
#define XPAD 448     // GEMM1 K padded (14 tiles of 32)
#define ZPAD 416     // GEMM2 K padded (13 tiles of 32)
#define EPS 1e-5f

typedef __attribute__((ext_vector_type(8))) short short8;
typedef __attribute__((ext_vector_type(4))) float f32x4;
typedef __attribute__((ext_vector_type(4))) unsigned int uint4v;

__device__ inline float bf2f(unsigned short u) {
    union { unsigned int i; float f; } v; v.i = (unsigned int)u << 16; return v.f;
}
__device__ inline unsigned short f2bf(float f) {
    union { float f; unsigned int i; } v; v.f = f;
    unsigned int r = (v.i + 0x7fff + ((v.i >> 16) & 1)) >> 16;
    return (unsigned short)r;
}

// direct global->LDS DMA, 16B per lane; lds dest = wave-uniform base + lane*16
typedef __attribute__((address_space(1))) const unsigned int g_u32;
typedef __attribute__((address_space(3))) unsigned int l_u32;
__device__ __forceinline__ void gload_lds16(const void* g, void* l) {
    __builtin_amdgcn_global_load_lds((g_u32*)g, (l_u32*)l, 16, 0, 0);
}

// ---------------- ws layout (bytes, all 16B-aligned) ----------------
#define X_OFF    0
#define Z1_OFF   14680064
#define W1S_OFF  28311552
#define W2S_OFF  28712960
#define BASE_OFF 29085696
#define ST_OFF   29151232

// =====================================================================
// gather (blocks 0..1023) + W-staging/stat-zero (blocks 1024..1212)
// =====================================================================
__global__ __launch_bounds__(256) void gather_prep(
    const int* __restrict__ Xcat, const float* __restrict__ Xdense,
    const float* __restrict__ fm1, const float* __restrict__ emb,
    const float* __restrict__ Wd, const float* __restrict__ bd,
    const float* __restrict__ W1, const float* __restrict__ W2,
    unsigned short* __restrict__ X, float* __restrict__ base,
    unsigned short* __restrict__ W1s, unsigned short* __restrict__ W2s,
    float* __restrict__ st)
{
    int tid = threadIdx.x;
    if (blockIdx.x >= 1024) {
        // ---------- prep path ----------
        int c = (blockIdx.x - 1024) * 256 + tid;     // 0..48383
        if (c < 256) {
            for (int i = tid; i < 1664; i += 256) st[i] = 0.f;
        }
        const float* W; unsigned short* dst; int K; int cc;
        if (c < 25088) { W = W1; dst = W1s; K = 429; cc = c; }
        else           { W = W2; dst = W2s; K = 400; cc = c - 25088; }
        int n  = cc % 448;
        int q  = (cc / 448) & 3;
        int kt = cc / 1792;
        unsigned short o[8];
        #pragma unroll
        for (int j = 0; j < 8; ++j) {
            int k = kt * 32 + q * 8 + j;
            float v = (n < NH && k < K) ? W[(size_t)k * NH + n] : 0.f;
            o[j] = f2bf(v);
        }
        *(uint4v*)(dst + (size_t)cc * 8) = *(uint4v*)o;
        return;
    }
    // ---------- gather path ----------
    int r = blockIdx.x * 16 + (tid >> 4);
    int k = tid & 15;
    const int* idxp = Xcat + (size_t)r * NF;
    unsigned short* xrow = X + (size_t)r * XPAD;

    float s = 0.f, ss = 0.f;
    #pragma unroll
    for (int f = 0; f < NF; ++f) {
        int idx = idxp[f];
        float v = emb[((size_t)f * NV + idx) * 16 + k];
        s += v; ss += v * v;
        xrow[f * 16 + k] = f2bf(v);
    }
    float fmsum = fm1[(size_t)k * NV + idxp[k]];
    if (k < NF - 16) fmsum += fm1[(size_t)(k + 16) * NV + idxp[k + 16]];
    float dsum = 0.f;
    if (k < ND) {
        float xd = Xdense[(size_t)r * ND + k];
        dsum = xd * Wd[k];
        xrow[NF * 16 + k] = f2bf(xd);
    }
    xrow[429 + k] = 0;
    if (k < 3) xrow[445 + k] = 0;

    float ix = s * s - ss;
    float rf = fmsum, rd = dsum;
    #pragma unroll
    for (int off = 8; off; off >>= 1) {
        ix += __shfl_xor(ix, off, 16);
        rf += __shfl_xor(rf, off, 16);
        rd += __shfl_xor(rd, off, 16);
    }
    if (k == 0) base[r] = 0.5f * ix + rf + rd + bd[0];
}

// =====================================================================
// MFMA GEMM, T3-minimum 2-phase pipeline with global_load_lds W staging.
// Per tile: [issue DMA for t+1] [af BN/convert] [ds_read + MFMA on t]
// [one __syncthreads = vmcnt/lgkm drain].
// grid = 256 x 512. wave wv: rows (wv&3)*16.., N-half (wv>>2).
// waves 0..6 each stage 4x64 16B-chunks of the next W tile (1792 total).
// =====================================================================
template<int NT, int LDA, bool APPLY_BN>
__global__ __launch_bounds__(512, 2) void mfma_gemm(
    const unsigned short* __restrict__ A,
    const unsigned short* __restrict__ Wst,
    const float* __restrict__ bias,
    const float* __restrict__ gsumIn, const float* __restrict__ gsqIn,
    const float* __restrict__ g, const float* __restrict__ be,
    unsigned short* __restrict__ Z, int ldz,
    float* __restrict__ gsum, float* __restrict__ gsq)
{
    __shared__ unsigned short b_s[2][14336];      // 57,344 B (W tile dbuf)
    __shared__ float sredS[4][416];               // 6,656 B
    __shared__ float sredQ[4][416];               // 6,656 B
    __shared__ float alpha_s[416], beta_s[416];   // 3,328 B

    const int tid = threadIdx.x;
    const int lane = tid & 63;
    const int wv = tid >> 6;             // 0..7
    const int rowgrp = wv & 3;
    const int nhalf = wv >> 2;
    const int l15 = lane & 15;
    const int qh = lane >> 4;            // 0..3
    const int m0 = blockIdx.x * 64;
    const int arow = m0 + rowgrp * 16 + l15;
    const int c0 = nhalf * 208;
    const int NFRAG = nhalf ? 12 : 13;

    if constexpr (APPLY_BN) {
        for (int c = tid; c < ZPAD; c += 512) {
            float a = 0.f, b = 0.f;
            if (c < NH) {
                float mean = gsumIn[c] * (1.f / B_ROWS);
                float var  = gsqIn[c] * (1.f / B_ROWS) - mean * mean;
                a = g[c] * rsqrtf(var + EPS);
                b = be[c] - mean * a;
            }
            alpha_s[c] = a; beta_s[c] = b;
        }
    }

    f32x4 acc[13];
    #pragma unroll
    for (int i = 0; i < 13; ++i) acc[i] = f32x4{0.f, 0.f, 0.f, 0.f};

    // DMA-stage W tile kt into buffer buf (waves 0..6 only)
    auto stage = [&](int kt, int buf) {
        #pragma unroll
        for (int i = 0; i < 4; ++i) {
            int cchunk = wv * 256 + i * 64 + lane;
            gload_lds16(Wst + (size_t)kt * 14336 + (size_t)cchunk * 8,
                        &b_s[buf][(size_t)(wv * 256 + i * 64) * 8]);
        }
    };

    if (wv < 7) stage(0, 0);
    short8 af_next = *(const short8*)(A + (size_t)arow * LDA + qh * 8);
    __syncthreads();    // tile 0 staged (vmcnt drained by barrier)

    for (int kt = 0; kt < NT; ++kt) {
        // issue next tile's DMA immediately; flies during this tile's compute
        if (kt + 1 < NT && wv < 7) stage(kt + 1, (kt + 1) & 1);

        short8 af = af_next;
        if (kt + 1 < NT)
            af_next = *(const short8*)(A + (size_t)arow * LDA + (kt + 1) * 32 + qh * 8);

        if constexpr (APPLY_BN) {
            const int k0 = kt * 32 + qh * 8;
            #pragma unroll
            for (int j = 0; j < 8; ++j) {
                float f = bf2f((unsigned short)af[j]);
                f = fmaxf(0.f, alpha_s[k0 + j] * f + beta_s[k0 + j]);
                af[j] = (short)f2bf(f);
            }
        }
        const unsigned short* bb = &b_s[kt & 1][(size_t)(qh * 448 + c0 + l15) * 8];
        #pragma unroll
        for (int nn = 0; nn < 13; ++nn) {
            if (nn < NFRAG) {
                short8 bf = *(const short8*)(bb + nn * 128);
                acc[nn] = __builtin_amdgcn_mfma_f32_16x16x32_bf16(af, bf, acc[nn], 0, 0, 0);
            }
        }
        __syncthreads();   // drains vmcnt (next tile staged) + protects buf reuse
    }

    // ---- epilogue: +bias, bf16 store, fp32 column stats ----
    #pragma unroll
    for (int nn = 0; nn < 13; ++nn) {
        if (nn < NFRAG) {
            int col = c0 + nn * 16 + l15;
            float bv = bias[col];
            float ps = 0.f, pq = 0.f;
            #pragma unroll
            for (int q = 0; q < 4; ++q) {
                float v = acc[nn][q] + bv;
                ps += v; pq += v * v;
                Z[(size_t)(m0 + rowgrp * 16 + qh * 4 + q) * ldz + col] = f2bf(v);
            }
            ps += __shfl_xor(ps, 16, 64); ps += __shfl_xor(ps, 32, 64);
            pq += __shfl_xor(pq, 16, 64); pq += __shfl_xor(pq, 32, 64);
            if (lane < 16) { sredS[rowgrp][col] = ps; sredQ[rowgrp][col] = pq; }
        }
    }
    if (nhalf == 1) {
        int col = NH + l15;
        if (col < ldz) {
            #pragma unroll
            for (int q = 0; q < 4; ++q)
                Z[(size_t)(m0 + rowgrp * 16 + qh * 4 + q) * ldz + col] = 0;
        }
    }
    __syncthreads();
    for (int c = tid; c < NH; c += 512) {
        float s = sredS[0][c] + sredS[1][c] + sredS[2][c] + sredS[3][c];
        float q = sredQ[0][c] + sredQ[1][c] + sredQ[2][c] + sredQ[3][c];
        atomicAdd(&gsum[c], s);
        atomicAdd(&gsq[c], q);
    }
}

// =====================================================================
// final: finalize BN2 in-block, then out[r] = base[r] + relu(.)·W3 + b3
// =====================================================================
__global__ __launch_bounds__(256) void final_kernel(
    const unsigned short* __restrict__ Z2,
    const float* __restrict__ gsum2, const float* __restrict__ gsq2,
    const float* __restrict__ g2, const float* __restrict__ be2,
    const float* __restrict__ W3, const float* __restrict__ b3,
    const float* __restrict__ base, float* __restrict__ out)
{
    __shared__ float a2s[NH], b2s[NH], w3s[NH];
    int tid = threadIdx.x;
    for (int c = tid; c < NH; c += 256) {
        float mean = gsum2[c] * (1.f / B_ROWS);
        float var  = gsq2[c] * (1.f / B_ROWS) - mean * mean;
        float a = g2[c] * rsqrtf(var + EPS);
        a2s[c] = a;
        b2s[c] = be2[c] - mean * a;
        w3s[c] = W3[c];
    }
    __syncthreads();
    int lane = tid & 63;
    int wv = tid >> 6;
    bool act = lane < 50;
    int cb = lane * 8;
    float al[8], bb[8], w3[8];
    #pragma unroll
    for (int j = 0; j < 8; ++j) {
        al[j] = act ? a2s[cb + j] : 0.f;
        bb[j] = act ? b2s[cb + j] : 0.f;
        w3[j] = act ? w3s[cb + j] : 0.f;
    }
    int r0 = blockIdx.x * 32 + wv * 8;
    float bias3 = b3[0];
    for (int t = 0; t < 8; t += 2) {
        int r = r0 + t;
        float acc0 = 0.f, acc1 = 0.f;
        if (act) {
            short8 z0 = *(const short8*)(Z2 + (size_t)r * ZPAD + cb);
            short8 z1 = *(const short8*)(Z2 + (size_t)(r + 1) * ZPAD + cb);
            #pragma unroll
            for (int j = 0; j < 8; ++j) {
                acc0 += fmaxf(0.f, al[j] * bf2f((unsigned short)z0[j]) + bb[j]) * w3[j];
                acc1 += fmaxf(0.f, al[j] * bf2f((unsigned short)z1[j]) + bb[j]) * w3[j];
            }
        }
        #pragma unroll
        for (int off = 32; off; off >>= 1) {
            acc0 += __shfl_xor(acc0, off, 64);
            acc1 += __shfl_xor(acc1, off, 64);
        }
        if (lane == 0) out[r] = base[r] + acc0 + bias3;
        if (lane == 1) out[r + 1] = base[r + 1] + acc1 + bias3;
    }
}

// =====================================================================
extern "C" void kernel_launch(void* const* d_in, const int* in_sizes, int n_in,
                              void* d_out, int out_size, void* d_ws, size_t ws_size,
                              hipStream_t stream)
{
    const int*   Xcat = (const int*)d_in[0];
    const float* Xd   = (const float*)d_in[1];
    const float* fm1  = (const float*)d_in[2];
    const float* emb  = (const float*)d_in[3];
    const float* Wd   = (const float*)d_in[4];
    const float* bd   = (const float*)d_in[5];
    const float* W1   = (const float*)d_in[6];
    const float* b1   = (const float*)d_in[7];
    const float* g1   = (const float*)d_in[8];
    const float* be1  = (const float*)d_in[9];
    const float* W2   = (const float*)d_in[10];
    const float* b2   = (const float*)d_in[11];
    const float* g2   = (const float*)d_in[12];
    const float* be2  = (const float*)d_in[13];
    const float* W3   = (const float*)d_in[14];
    const float* b3   = (const float*)d_in[15];

    char* ws = (char*)d_ws;
    unsigned short* X   = (unsigned short*)(ws + X_OFF);
    unsigned short* Z1  = (unsigned short*)(ws + Z1_OFF);
    unsigned short* Z2  = X;   // X dead after GEMM1
    unsigned short* W1s = (unsigned short*)(ws + W1S_OFF);
    unsigned short* W2s = (unsigned short*)(ws + W2S_OFF);
    float* base = (float*)(ws + BASE_OFF);
    float* st   = (float*)(ws + ST_OFF);
    float* gsum1 = st;          float* gsq1 = st + 416;
    float* gsum2 = st + 832;    float* gsq2 = st + 1248;
    float* out = (float*)d_out;

    gather_prep<<<1213, 256, 0, stream>>>(Xcat, Xd, fm1, emb, Wd, bd, W1, W2,
                                          X, base, W1s, W2s, st);

    mfma_gemm<14, XPAD, false><<<256, 512, 0, stream>>>(
        X, W1s, b1, nullptr, nullptr, nullptr, nullptr, Z1, ZPAD, gsum1, gsq1);

    mfma_gemm<13, ZPAD, true><<<256, 512, 0, stream>>>(
        Z1, W2s, b2, gsum1, gsq1, g1, be1, Z2, ZPAD, gsum2, gsq2);

    final_kernel<<<512, 256, 0, stream>>>(Z2, gsum2, gsq2, g2, be2, W3, b3, base, out);
}